// Round 3
// baseline (83.433 us; speedup 1.0000x reference)
//
#include <hip/hip_runtime.h>

#define N_FFT 1024
#define SPLIT0 513
// Swizzle in float2 units: pad 1 float2 every 16 (breaks pow-2 write strides).
#define PAD2(a) ((a) + ((a) >> 4))

// One block per PAIR of rows: z = row0 + i*row1, one 1024-pt complex FFT
// (radix-4 Stockham autosort, 5 passes, float2 LDS), untangle two real spectra.
__global__ __launch_bounds__(256) void rfft1024_pairs(const float* __restrict__ x,
                                                      float* __restrict__ out,
                                                      int nrows) {
    __shared__ float2 buf[2][N_FFT + 64];

    const int t = threadIdx.x;
    const int pair = blockIdx.x;
    const float* __restrict__ r0 = x + (size_t)(2 * pair) * N_FFT;
    const float* __restrict__ r1 = r0 + N_FFT;

    // Load: z[i] = row0[i] + i*row1[i]; coalesced dword loads, b64 LDS writes
    // at consecutive float2 addresses (conflict-free).
    #pragma unroll
    for (int c = 0; c < 4; ++c) {
        int i = t + 256 * c;
        buf[0][PAD2(i)] = make_float2(r0[i], r1[i]);
    }
    __syncthreads();

    const float CANG = -6.2831853071795864769f / 1024.0f;
    int src = 0;

    // 5 radix-4 Stockham DIF passes. Pass p: m = 4^p.
    // Thread t: k = t & (m-1), jm = t - k. Reads src[t + 256r] (contiguous).
    // Twiddle: w = exp(-2*pi*i*jm/1024). Writes dst[k + 4*jm + r*m].
    #pragma unroll
    for (int p = 0; p < 5; ++p) {
        const int m = 1 << (2 * p);
        const int k = t & (m - 1);
        const int jm = t - k;

        float2 a = buf[src][PAD2(t)];
        float2 b = buf[src][PAD2(t + 256)];
        float2 c = buf[src][PAD2(t + 512)];
        float2 d = buf[src][PAD2(t + 768)];

        float t0r = a.x + c.x, t0i = a.y + c.y;
        float t1r = a.x - c.x, t1i = a.y - c.y;
        float t2r = b.x + d.x, t2i = b.y + d.y;
        float t3r = b.x - d.x, t3i = b.y - d.y;

        float y0r = t0r + t2r, y0i = t0i + t2i;
        float y1r = t1r + t3i, y1i = t1i - t3r;  // t1 + (-i)*t3
        float y2r = t0r - t2r, y2i = t0i - t2i;
        float y3r = t1r - t3i, y3i = t1i + t3r;  // t1 - (-i)*t3

        float ang = CANG * (float)jm;
        float s1, c1;
        __sincosf(ang, &s1, &c1);
        float c2 = c1 * c1 - s1 * s1, s2 = 2.0f * c1 * s1;
        float c3 = c1 * c2 - s1 * s2, s3 = c1 * s2 + s1 * c2;

        const int dst = src ^ 1;
        const int w0 = k + 4 * jm;
        buf[dst][PAD2(w0)]         = make_float2(y0r, y0i);
        buf[dst][PAD2(w0 + m)]     = make_float2(y1r * c1 - y1i * s1, y1r * s1 + y1i * c1);
        buf[dst][PAD2(w0 + 2 * m)] = make_float2(y2r * c2 - y2i * s2, y2r * s2 + y2i * c2);
        buf[dst][PAD2(w0 + 3 * m)] = make_float2(y3r * c3 - y3i * s3, y3r * s3 + y3i * c3);
        __syncthreads();
        src ^= 1;
    }

    // Untangle: X0[k] = (Z[k]+conj(Z[N-k]))/2 ; X1[k] = -i/2*(Z[k]-conj(Z[N-k])).
    const size_t row0 = (size_t)(2 * pair);
    float* __restrict__ outr = out;
    float* __restrict__ outi = out + (size_t)nrows * SPLIT0;

    #pragma unroll
    for (int c = 0; c < 2; ++c) {
        int kk = t + 256 * c;
        float2 z = buf[src][PAD2(kk)];
        int km = (N_FFT - kk) & (N_FFT - 1);
        float2 zm = buf[src][PAD2(km)];
        float X0r = 0.5f * (z.x + zm.x), X0i = 0.5f * (z.y - zm.y);
        float X1r = 0.5f * (z.y + zm.y), X1i = 0.5f * (zm.x - z.x);
        outr[row0 * SPLIT0 + kk]       = X0r;
        outi[row0 * SPLIT0 + kk]       = X0i;
        outr[(row0 + 1) * SPLIT0 + kk] = X1r;
        outi[(row0 + 1) * SPLIT0 + kk] = X1i;
    }
    if (t == 0) {
        // k = 512 (Nyquist): Z[512] = X0[512] + i*X1[512], both real.
        float2 z = buf[src][PAD2(512)];
        outr[row0 * SPLIT0 + 512]       = z.x;
        outi[row0 * SPLIT0 + 512]       = 0.0f;
        outr[(row0 + 1) * SPLIT0 + 512] = z.y;
        outi[(row0 + 1) * SPLIT0 + 512] = 0.0f;
    }
}

extern "C" void kernel_launch(void* const* d_in, const int* in_sizes, int n_in,
                              void* d_out, int out_size, void* d_ws, size_t ws_size,
                              hipStream_t stream) {
    const float* x = (const float*)d_in[0];
    float* out = (float*)d_out;
    const int nrows = in_sizes[0] / N_FFT;  // 8192
    rfft1024_pairs<<<nrows / 2, 256, 0, stream>>>(x, out, nrows);
}